// Round 16
// baseline (96.174 us; speedup 1.0000x reference)
//
#include <hip/hip_runtime.h>
#include <math.h>

#define N_NODES 20000
#define N_EDGES 160000
#define EPAD    160256
#define NTILES  1250

#define PI_F 3.14159265358979323846f
#define LN2_F 0.69314718055994530942f

#define W1PK 43008
#define W23PK 4096
#define WPK_LAYER 51200
#define XROW 680           // LDS X row stride in u16
#define CAP 312            // mi LDS row stride in u16 (624B; 156dw%32=28 -> 2-way banks)
#define NFILL_MAX 272      // fill cap (mean 128, +12 sigma); reads <= 272+31 < 312

#define NW_EDGE 626        // edge_wt tiles
#define NW_XI   625        // xi_init_h tiles
#define NW_PACK 600        // pack_w tiles
#define NW_ROW  79         // row_start tiles
#define NW_TOTAL (NW_EDGE + NW_XI + NW_PACK + NW_ROW)   // 1930

typedef short short8v __attribute__((ext_vector_type(8)));
typedef float f32x4 __attribute__((ext_vector_type(4)));
typedef unsigned short u16;
typedef unsigned long long ull;

__device__ __forceinline__ float sspf(float x) {
    return fmaxf(x, 0.0f) + log1pf(expf(-fabsf(x))) - LN2_F;
}
__device__ __forceinline__ u16 f2bf(float f) {
    unsigned int u = __float_as_uint(f);
    return (u16)((u + 0x7fffu + ((u >> 16) & 1u)) >> 16);
}
__device__ __forceinline__ unsigned int pk2(float a, float b) {
    return (unsigned int)f2bf(a) | ((unsigned int)f2bf(b) << 16);
}
// mask of 4 u16 slots: slots j >= t are 0xFFFF (t clamped to [0,4])
__device__ __forceinline__ ull mge(int t) {
    t = t < 0 ? 0 : (t > 4 ? 4 : t);
    return t == 4 ? 0ULL : (~0ULL << (t * 16));
}

// ======================= setup works (shared smem) ==========================

__device__ void edge_wt_work(int blk, const float* __restrict__ dist,
                             const float* __restrict__ sw,
                             const float* __restrict__ bo,
                             u16* __restrict__ WT, char* smem)
{
    u16 (*tr)[264] = reinterpret_cast<u16(*)[264]>(smem);   // 21120 B
    int tid = threadIdx.x;
    int e = blk * 256 + tid;

    if (e < N_EDGES) {
        float r = dist[e];
        float c = sqrtf(0.4f) / r * sw[e];
        float rbv[8];
        #pragma unroll
        for (int n = 0; n < 8; ++n)
            rbv[n] = c * sinf((float)(n + 1) * PI_F * r * 0.2f);
        float bov[5];
        #pragma unroll
        for (int b = 0; b < 5; ++b) bov[b] = bo[(size_t)e * 5 + b];
        #pragma unroll
        for (int n = 0; n < 8; ++n)
            #pragma unroll
            for (int b = 0; b < 5; ++b)
                tr[n * 5 + b][tid] = f2bf(rbv[n] * bov[b]);
    } else {
        #pragma unroll
        for (int j = 0; j < 40; ++j) tr[j][tid] = 0;
    }
    __syncthreads();

    #pragma unroll
    for (int i = 0; i < 5; ++i) {
        int qq = tid + i * 256;
        int s = qq >> 5, c = qq & 31;
        uint4 v = *reinterpret_cast<const uint4*>(&tr[s][c * 8]);
        *reinterpret_cast<uint4*>(WT + (size_t)s * EPAD + blk * 256 + c * 8) = v;
    }
}

__device__ void row_start_work(int blk, const int* __restrict__ src,
                               int* __restrict__ row)
{
    int i = blk * 256 + threadIdx.x;
    if (i > N_NODES) return;
    int lo = 0, hi = N_EDGES;
    while (lo < hi) {
        int mid = (lo + hi) >> 1;
        if (src[mid] < i) lo = mid + 1; else hi = mid;
    }
    row[i] = lo;
}

__device__ void pack_w_work(int blk, const float* __restrict__ fcW1,
                            const float* __restrict__ fcW2,
                            const float* __restrict__ fcW3,
                            u16* __restrict__ Wpk)
{
    int idx = blk * 256 + threadIdx.x;
    if (idx >= 3 * WPK_LAYER) return;
    int layer = idx / WPK_LAYER;
    int r = idx - layer * WPK_LAYER;
    float val = 0.0f;
    if (r < W1PK) {
        int e = r;
        int j = e & 7, lane = (e >> 3) & 63, c16 = (e >> 9) & 3, ks = e >> 11;
        int k = ks * 32 + (lane >> 4) * 8 + j;
        int colm = c16 * 16 + (lane & 15);
        if (k < 640) {
            int nbv = k >> 4, ss = k & 15;
            int nn = nbv / 5, bb = nbv - nn * 5;
            val = fcW1[(size_t)layer * 656 * 64 + (size_t)(nn * 80 + ss * 5 + bb) * 64 + colm];
        } else if (k < 656) {
            val = fcW1[(size_t)layer * 656 * 64 + (size_t)k * 64 + colm];
        }
    } else {
        bool is2 = (r < W1PK + W23PK);
        const float* W = is2 ? fcW2 : fcW3;
        int e = is2 ? (r - W1PK) : (r - W1PK - W23PK);
        int j = e & 7, lane = (e >> 3) & 63, c16 = (e >> 9) & 3, ks = e >> 11;
        int k = ks * 32 + (lane >> 4) * 8 + j;
        int colm = c16 * 16 + (lane & 15);
        val = W[(size_t)layer * 64 * 64 + (size_t)k * 64 + colm];
    }
    Wpk[(size_t)layer * WPK_LAYER + r] = f2bf(val);
}

__device__ void xi_init_h_work(int blk, const int* __restrict__ species,
                               const float* __restrict__ Wsp,
                               const float* __restrict__ Wl0,
                               const float* __restrict__ bl0,
                               float* __restrict__ xi,
                               float* __restrict__ h, char* smem)
{
    float* xs = reinterpret_cast<float*>(smem);            //  8192 B
    float* ws = reinterpret_cast<float*>(smem + 8192);     //  8192 B
    int tid = threadIdx.x;
    int nb = blk * 32;

    #pragma unroll
    for (int i = 0; i < 2; ++i) {
        int idx = tid + i * 256;
        int node = idx >> 4, c4 = idx & 15;
        int sp = species[nb + node];
        float4 v = reinterpret_cast<const float4*>(Wsp + (size_t)sp * 64)[c4];
        reinterpret_cast<float4*>(xs)[idx] = v;
        reinterpret_cast<float4*>(xi)[(size_t)(nb + node) * 16 + c4] = v;
    }
    {
        const float4* wsrc = reinterpret_cast<const float4*>(Wl0);
        float4* wd = reinterpret_cast<float4*>(ws);
        #pragma unroll
        for (int i = 0; i < 2; ++i) wd[tid + i * 256] = wsrc[tid + i * 256];
    }
    __syncthreads();

    int c4g = tid & 7;
    int nrow = tid >> 3;
    float4 acc = *reinterpret_cast<const float4*>(bl0 + c4g * 4);
    const float* xr = xs + nrow * 64;
    #pragma unroll 8
    for (int j = 0; j < 64; ++j) {
        float xv = xr[j];
        float4 wv = *reinterpret_cast<const float4*>(ws + j * 32 + c4g * 4);
        acc.x = fmaf(xv, wv.x, acc.x);
        acc.y = fmaf(xv, wv.y, acc.y);
        acc.z = fmaf(xv, wv.z, acc.z);
        acc.w = fmaf(xv, wv.w, acc.w);
    }
    *reinterpret_cast<float4*>(h + (size_t)(nb + nrow) * 32 + c4g * 4) = acc;
}

// ======================= merged setup kernel (1 dispatch) ===================
__global__ __launch_bounds__(256) void setup_kernel(
    const float* __restrict__ dist, const float* __restrict__ sw,
    const float* __restrict__ bo, u16* __restrict__ WT,
    const int* __restrict__ species, const float* __restrict__ Wsp,
    const float* __restrict__ Wl0, const float* __restrict__ bl0,
    float* __restrict__ xi, float* __restrict__ h0,
    const float* __restrict__ fcW1, const float* __restrict__ fcW2,
    const float* __restrict__ fcW3, u16* __restrict__ Wpk,
    const int* __restrict__ esrc, int* __restrict__ rowp)
{
    __shared__ __align__(16) char smem[21760];
    int wk = blockIdx.x;
    if (wk < NW_EDGE)
        edge_wt_work(wk, dist, sw, bo, WT, smem);
    else if (wk < NW_EDGE + NW_XI)
        xi_init_h_work(wk - NW_EDGE, species, Wsp, Wl0, bl0, xi, h0, smem);
    else if (wk < NW_EDGE + NW_XI + NW_PACK)
        pack_w_work(wk - NW_EDGE - NW_XI, fcW1, fcW2, fcW3, Wpk);
    else
        row_start_work(wk - NW_EDGE - NW_XI - NW_PACK, esrc, rowp);
}

// ======================= fused per-layer kernel =============================
// LDS 31744 B -> 5 blocks/CU (was 34304 -> 4). Everything else R15-identical.
__global__ __launch_bounds__(256) void agg_fc_fused(
    const u16* __restrict__ WT,             // [48][EPAD] bf16 (rows 40..47 unused)
    const int* __restrict__ row,
    const int* __restrict__ dst,
    const float* __restrict__ h_in,         // N x 32
    float* __restrict__ h_out,              // N x 32 (next layer)
    const u16* __restrict__ Wpk,
    const float* __restrict__ b1,
    const float* __restrict__ b2,
    const float* __restrict__ b3,
    const float* __restrict__ Wl_next,      // 64 x 32 (if do_h)
    const float* __restrict__ bl_next,      // 32
    int do_h,
    float* __restrict__ xi)
{
    __shared__ __align__(16) char smem[21760 + 16 * CAP * 2];   // 31744 B
    u16 (*Xs)[XROW] = reinterpret_cast<u16(*)[XROW]>(smem);
    u16* mi  = reinterpret_cast<u16*>(smem + 21760);            // [16][CAP]
    u16* Y1  = reinterpret_cast<u16*>(smem + 21760);            // aliases mi
    u16* Y2  = reinterpret_cast<u16*>(smem + 21760 + 2304);
    float* Yo = reinterpret_cast<float*>(smem + 21760 + 4608);  // 16 x 68 f32
    float* Wlds = reinterpret_cast<float*>(smem);               // aliases Xs
    float* Xn   = reinterpret_cast<float*>(smem + 8192);        // 16 x 68 f32

    int tid = threadIdx.x;
    int wv = tid >> 6;
    int lane = tid & 63;
    int s = lane & 15;
    int kg = lane >> 4;
    int n0 = blockIdx.x * 16;
    int base = n0 + (wv << 2);

    int E0 = row[n0];
    int E1 = row[n0 + 16];
    int G0 = E0 & ~7;
    int nfill = E1 - G0;
    if (nfill > NFILL_MAX) nfill = NFILL_MAX;

    // ---- si staging + zero pad ----
    {
        int t = kg;
        u16* xr = &Xs[(wv << 2) + t][0];
        xr[640 + s] = f2bf(h_in[(size_t)(base + t) * 32 + s]);
        xr[656 + s] = 0;
    }

    // ---- block-local mi gather: thread-per-edge ----
    for (int i = tid; i < nfill; i += 256) {
        int d = dst[G0 + i];
        const float4* hp = reinterpret_cast<const float4*>(h_in + (size_t)d * 32 + 16);
        float4 v0 = hp[0], v1 = hp[1], v2 = hp[2], v3 = hp[3];
        u16* col = mi + i;
        col[0 * CAP]  = f2bf(v0.x); col[1 * CAP]  = f2bf(v0.y);
        col[2 * CAP]  = f2bf(v0.z); col[3 * CAP]  = f2bf(v0.w);
        col[4 * CAP]  = f2bf(v1.x); col[5 * CAP]  = f2bf(v1.y);
        col[6 * CAP]  = f2bf(v1.z); col[7 * CAP]  = f2bf(v1.w);
        col[8 * CAP]  = f2bf(v2.x); col[9 * CAP]  = f2bf(v2.y);
        col[10 * CAP] = f2bf(v2.z); col[11 * CAP] = f2bf(v2.w);
        col[12 * CAP] = f2bf(v3.x); col[13 * CAP] = f2bf(v3.y);
        col[14 * CAP] = f2bf(v3.z); col[15 * CAP] = f2bf(v3.w);
    }
    __syncthreads();

    // ======== Phase A: streaming MFMA aggregation ========
    for (int t = 0; t < 4; ++t) {
        int node = base + t;
        int e0 = row[node], e1 = row[node + 1];
        int e0a = e0 & ~7;
        int L0 = e0a - G0;                       // local aligned start (8-aligned)
        int nks = (e1 - e0a + 31) >> 5;

        f32x4 c0 = {0.f, 0.f, 0.f, 0.f};
        f32x4 c1 = {0.f, 0.f, 0.f, 0.f};
        f32x4 c2 = {0.f, 0.f, 0.f, 0.f};

        for (int kc = 0; kc < nks; ++kc) {
            int ebg = e0a + kc * 32 + kg * 8;    // global (WT, masks)
            int ebl = L0 + kc * 32 + kg * 8;     // local (mi LDS)
            uint4 bu = *reinterpret_cast<const uint4*>(mi + s * CAP + ebl);
            {
                int lo = e0 - ebg, hi = e1 - ebg;
                ull vA = mge(lo) & ~mge(hi);
                ull vB = mge(lo - 4) & ~mge(hi - 4);
                ull* bp = reinterpret_cast<ull*>(&bu);
                bp[0] &= vA;
                bp[1] &= vB;
            }
            short8v bfrag = *reinterpret_cast<short8v*>(&bu);
            const u16* ap = WT + (size_t)s * EPAD + ebg;
            short8v a0 = *reinterpret_cast<const short8v*>(ap);
            short8v a1 = *reinterpret_cast<const short8v*>(ap + (size_t)16 * EPAD);
            short8v a2 = *reinterpret_cast<const short8v*>(ap + (size_t)32 * EPAD);
            c0 = __builtin_amdgcn_mfma_f32_16x16x32_bf16(a0, bfrag, c0, 0, 0, 0);
            c1 = __builtin_amdgcn_mfma_f32_16x16x32_bf16(a1, bfrag, c1, 0, 0, 0);
            c2 = __builtin_amdgcn_mfma_f32_16x16x32_bf16(a2, bfrag, c2, 0, 0, 0);
        }

        u16* xr = &Xs[(wv << 2) + t][0];
        #pragma unroll
        for (int q = 0; q < 4; ++q) {
            xr[(kg * 4 + q) * 16 + s]      = f2bf(c0[q]);
            xr[(16 + kg * 4 + q) * 16 + s] = f2bf(c1[q]);
        }
        if (kg < 2) {
            #pragma unroll
            for (int q = 0; q < 4; ++q)
                xr[(32 + kg * 4 + q) * 16 + s] = f2bf(c2[q]);
        }
    }
    __syncthreads();

    // ======== FC chain ========
    int w = wv;
    int lrow = lane & 15;
    int lk = lane >> 4;
    int col = w * 16 + lrow;

    const u16* Wpk1 = Wpk;
    const u16* Wpk2 = Wpk + W1PK;
    const u16* Wpk3 = Wpk + W1PK + W23PK;

    // ---- FC1: K = 672 ----
    f32x4 acc;
    {
        float bv = b1[col];
        acc[0] = bv; acc[1] = bv; acc[2] = bv; acc[3] = bv;
    }
    const u16* wp = Wpk1 + ((size_t)w * 64 + lane) * 8;
    #pragma unroll
    for (int ks = 0; ks < 21; ++ks) {
        short8v a = *reinterpret_cast<const short8v*>(&Xs[lrow][ks * 32 + lk * 8]);
        short8v b = *reinterpret_cast<const short8v*>(wp + (size_t)ks * 2048);
        acc = __builtin_amdgcn_mfma_f32_16x16x32_bf16(a, b, acc, 0, 0, 0);
    }
    __syncthreads();   // mi region fully dead before Y1 writes (mi aliased)
    #pragma unroll
    for (int q = 0; q < 4; ++q)
        Y1[(lk * 4 + q) * 72 + col] = f2bf(sspf(acc[q]));
    __syncthreads();

    // stage Wl_next into dead Xs region (concurrent with FC2/FC3)
    if (do_h) {
        const float4* wsrc = reinterpret_cast<const float4*>(Wl_next);
        float4* wd = reinterpret_cast<float4*>(Wlds);
        wd[tid] = wsrc[tid];
        wd[tid + 256] = wsrc[tid + 256];
    }

    // ---- FC2: K = 64 ----
    {
        float bv = b2[col];
        acc[0] = bv; acc[1] = bv; acc[2] = bv; acc[3] = bv;
    }
    #pragma unroll
    for (int ks = 0; ks < 2; ++ks) {
        short8v a = *reinterpret_cast<const short8v*>(&Y1[lrow * 72 + ks * 32 + lk * 8]);
        short8v b = *reinterpret_cast<const short8v*>(Wpk2 + ((size_t)(ks * 4 + w) * 64 + lane) * 8);
        acc = __builtin_amdgcn_mfma_f32_16x16x32_bf16(a, b, acc, 0, 0, 0);
    }
    __syncthreads();
    #pragma unroll
    for (int q = 0; q < 4; ++q)
        Y2[(lk * 4 + q) * 72 + col] = f2bf(sspf(acc[q]));
    __syncthreads();

    // ---- FC3: K = 64 ----
    {
        float bv = b3[col];
        acc[0] = bv; acc[1] = bv; acc[2] = bv; acc[3] = bv;
    }
    #pragma unroll
    for (int ks = 0; ks < 2; ++ks) {
        short8v a = *reinterpret_cast<const short8v*>(&Y2[lrow * 72 + ks * 32 + lk * 8]);
        short8v b = *reinterpret_cast<const short8v*>(Wpk3 + ((size_t)(ks * 4 + w) * 64 + lane) * 8);
        acc = __builtin_amdgcn_mfma_f32_16x16x32_bf16(a, b, acc, 0, 0, 0);
    }
    #pragma unroll
    for (int q = 0; q < 4; ++q)
        Yo[(lk * 4 + q) * 68 + col] = acc[q];
    __syncthreads();

    // ---- residual update (+ stash xi_new for h epilogue) ----
    {
        int rr = tid >> 4;
        int cc = tid & 15;
        float4 dv = *reinterpret_cast<const float4*>(Yo + rr * 68 + cc * 4);
        float4* xpn = reinterpret_cast<float4*>(xi + (size_t)(n0 + rr) * 64 + cc * 4);
        float4 o = *xpn;
        o.x += dv.x; o.y += dv.y; o.z += dv.z; o.w += dv.w;
        *xpn = o;
        if (do_h)
            *reinterpret_cast<float4*>(Xn + rr * 68 + cc * 4) = o;
    }

    // ---- h_next for own 16 nodes ----
    if (do_h) {
        __syncthreads();
        int node = tid >> 4;
        int c2 = (tid & 15) * 2;
        const float* xnr = Xn + node * 68;
        float h0 = bl_next[c2], h1 = bl_next[c2 + 1];
        #pragma unroll 8
        for (int j = 0; j < 64; ++j) {
            float xv = xnr[j];
            h0 = fmaf(xv, Wlds[j * 32 + c2], h0);
            h1 = fmaf(xv, Wlds[j * 32 + c2 + 1], h1);
        }
        *reinterpret_cast<float2*>(h_out + (size_t)(n0 + node) * 32 + c2) =
            make_float2(h0, h1);
    }
}

// ---------------------------------------------------------------------------
extern "C" void kernel_launch(void* const* d_in, const int* in_sizes, int n_in,
                              void* d_out, int out_size, void* d_ws, size_t ws_size,
                              hipStream_t stream) {
    const int*   species = (const int*)d_in[0];
    const int*   esrc    = (const int*)d_in[1];
    const int*   edst    = (const int*)d_in[2];
    const float* dist    = (const float*)d_in[3];
    const float* sw      = (const float*)d_in[4];
    const float* bo      = (const float*)d_in[5];
    const float* Wsp     = (const float*)d_in[6];
    const float* Wl      = (const float*)d_in[7];
    const float* bl      = (const float*)d_in[8];
    const float* fcW1    = (const float*)d_in[9];
    const float* fcb1    = (const float*)d_in[10];
    const float* fcW2    = (const float*)d_in[11];
    const float* fcb2    = (const float*)d_in[12];
    const float* fcW3    = (const float*)d_in[13];
    const float* fcb3    = (const float*)d_in[14];
    float* xi = (float*)d_out;

    char* ws = (char*)d_ws;
    u16*   WT   = (u16*)ws;                     // 48*EPAD*2 = 15,384,576 B
    int*   rowp = (int*)(ws + 15384576);        //     80,128 B
    float* h0   = (float*)(ws + 15464704);      //  2,560,000 B
    float* h1   = (float*)(ws + 18024704);      //  2,560,000 B
    u16*   Wpk  = (u16*)(ws + 20584704);        //    307,200 B

    hipLaunchKernelGGL(setup_kernel, dim3(NW_TOTAL), dim3(256), 0, stream,
                       dist, sw, bo, WT,
                       species, Wsp, Wl, bl, xi, h0,
                       fcW1, fcW2, fcW3, Wpk,
                       esrc, rowp);

    float* hbuf[2] = {h0, h1};
    for (int l = 0; l < 3; ++l) {
        int do_h = (l < 2) ? 1 : 0;
        int lnext = do_h ? (l + 1) : l;
        hipLaunchKernelGGL(agg_fc_fused, dim3(NTILES), dim3(256), 0, stream,
                           WT, rowp, edst,
                           hbuf[l & 1], hbuf[(l + 1) & 1],
                           Wpk + (size_t)l * WPK_LAYER,
                           fcb1 + (size_t)l * 64, fcb2 + (size_t)l * 64,
                           fcb3 + (size_t)l * 64,
                           Wl + (size_t)lnext * 64 * 32,
                           bl + (size_t)lnext * 32,
                           do_h, xi);
    }
}

// Round 17
// 87.322 us; speedup vs baseline: 1.1014x; 1.1014x over previous
//
#include <hip/hip_runtime.h>
#include <math.h>

#define N_NODES 20000
#define N_EDGES 160000
#define EPAD    160256
#define NGROUPS (EPAD / 8)     // 20032 8-edge groups
#define GSTRIDE 384            // u16 per group: 48 rows x 8
#define NTILES  1250

#define PI_F 3.14159265358979323846f
#define LN2_F 0.69314718055994530942f

#define W1PK 43008
#define W23PK 4096
#define WPK_LAYER 51200
#define XROW 680           // LDS X row stride in u16
#define CAP 312            // mi LDS row stride in u16 (624B; 156dw%32=28 -> 2-way banks)
#define NFILL_MAX 272      // fill cap (mean 128, +12 sigma); reads <= 272+31 < 312

#define NW_EDGE 626        // edge_wt tiles (256 edges = 32 groups each)
#define NW_XI   625
#define NW_PACK 600
#define NW_ROW  79
#define NW_TOTAL (NW_EDGE + NW_XI + NW_PACK + NW_ROW)   // 1930

typedef short short8v __attribute__((ext_vector_type(8)));
typedef float f32x4 __attribute__((ext_vector_type(4)));
typedef unsigned short u16;
typedef unsigned long long ull;

__device__ __forceinline__ float sspf(float x) {
    return fmaxf(x, 0.0f) + log1pf(expf(-fabsf(x))) - LN2_F;
}
__device__ __forceinline__ u16 f2bf(float f) {
    unsigned int u = __float_as_uint(f);
    return (u16)((u + 0x7fffu + ((u >> 16) & 1u)) >> 16);
}
__device__ __forceinline__ unsigned int pk2(float a, float b) {
    return (unsigned int)f2bf(a) | ((unsigned int)f2bf(b) << 16);
}
// mask of 4 u16 slots: slots j >= t are 0xFFFF (t clamped to [0,4])
__device__ __forceinline__ ull mge(int t) {
    t = t < 0 ? 0 : (t > 4 ? 4 : t);
    return t == 4 ? 0ULL : (~0ULL << (t * 16));
}

// ======================= setup works (shared smem) ==========================
// WTg[g][r][j]: group g = e>>3, row r = n*5+b (40..47 zero), j = e&7.
// Wave A-fragment loads become 768B-contiguous per group.
__device__ void edge_wt_work(int blk, const float* __restrict__ dist,
                             const float* __restrict__ sw,
                             const float* __restrict__ bo,
                             u16* __restrict__ WTg, char* smem)
{
    u16 (*tr)[264] = reinterpret_cast<u16(*)[264]>(smem);   // 21120 B
    int tid = threadIdx.x;
    int e = blk * 256 + tid;

    if (e < N_EDGES) {
        float r = dist[e];
        float c = sqrtf(0.4f) / r * sw[e];
        float th = PI_F * r * 0.2f;
        float s1, c1;
        __sincosf(th, &s1, &c1);
        float k2c = 2.0f * c1;
        float rbv[8];
        rbv[0] = s1;
        float sp = 0.0f, sc = s1;
        #pragma unroll
        for (int n = 1; n < 8; ++n) {
            float sn = k2c * sc - sp;
            rbv[n] = sn;
            sp = sc; sc = sn;
        }
        #pragma unroll
        for (int n = 0; n < 8; ++n) rbv[n] *= c;
        float bov[5];
        #pragma unroll
        for (int b = 0; b < 5; ++b) bov[b] = bo[(size_t)e * 5 + b];
        #pragma unroll
        for (int n = 0; n < 8; ++n)
            #pragma unroll
            for (int b = 0; b < 5; ++b)
                tr[n * 5 + b][tid] = f2bf(rbv[n] * bov[b]);
    } else {
        #pragma unroll
        for (int j = 0; j < 40; ++j) tr[j][tid] = 0;
    }
    __syncthreads();

    // write 32 groups x 48 rows x 8 u16, coalesced (rows 40..47 zeroed)
    #pragma unroll
    for (int i = 0; i < 6; ++i) {
        int r = i * 8 + (tid & 7);
        int gl = tid >> 3;                       // 0..31
        uint4 v = make_uint4(0u, 0u, 0u, 0u);
        if (r < 40) v = *reinterpret_cast<const uint4*>(&tr[r][gl * 8]);
        *reinterpret_cast<uint4*>(
            WTg + ((size_t)(blk * 32 + gl) * GSTRIDE + r * 8)) = v;
    }
}

__device__ void row_start_work(int blk, const int* __restrict__ src,
                               int* __restrict__ row)
{
    int i = blk * 256 + threadIdx.x;
    if (i > N_NODES) return;
    int lo = 0, hi = N_EDGES;
    while (lo < hi) {
        int mid = (lo + hi) >> 1;
        if (src[mid] < i) lo = mid + 1; else hi = mid;
    }
    row[i] = lo;
}

__device__ void pack_w_work(int blk, const float* __restrict__ fcW1,
                            const float* __restrict__ fcW2,
                            const float* __restrict__ fcW3,
                            u16* __restrict__ Wpk)
{
    int idx = blk * 256 + threadIdx.x;
    if (idx >= 3 * WPK_LAYER) return;
    int layer = idx / WPK_LAYER;
    int r = idx - layer * WPK_LAYER;
    float val = 0.0f;
    if (r < W1PK) {
        int e = r;
        int j = e & 7, lane = (e >> 3) & 63, c16 = (e >> 9) & 3, ks = e >> 11;
        int k = ks * 32 + (lane >> 4) * 8 + j;
        int colm = c16 * 16 + (lane & 15);
        if (k < 640) {
            int nbv = k >> 4, ss = k & 15;
            int nn = nbv / 5, bb = nbv - nn * 5;
            val = fcW1[(size_t)layer * 656 * 64 + (size_t)(nn * 80 + ss * 5 + bb) * 64 + colm];
        } else if (k < 656) {
            val = fcW1[(size_t)layer * 656 * 64 + (size_t)k * 64 + colm];
        }
    } else {
        bool is2 = (r < W1PK + W23PK);
        const float* W = is2 ? fcW2 : fcW3;
        int e = is2 ? (r - W1PK) : (r - W1PK - W23PK);
        int j = e & 7, lane = (e >> 3) & 63, c16 = (e >> 9) & 3, ks = e >> 11;
        int k = ks * 32 + (lane >> 4) * 8 + j;
        int colm = c16 * 16 + (lane & 15);
        val = W[(size_t)layer * 64 * 64 + (size_t)k * 64 + colm];
    }
    Wpk[(size_t)layer * WPK_LAYER + r] = f2bf(val);
}

__device__ void xi_init_h_work(int blk, const int* __restrict__ species,
                               const float* __restrict__ Wsp,
                               const float* __restrict__ Wl0,
                               const float* __restrict__ bl0,
                               float* __restrict__ xi,
                               float* __restrict__ h, char* smem)
{
    float* xs = reinterpret_cast<float*>(smem);            //  8192 B
    float* ws = reinterpret_cast<float*>(smem + 8192);     //  8192 B
    int tid = threadIdx.x;
    int nb = blk * 32;

    #pragma unroll
    for (int i = 0; i < 2; ++i) {
        int idx = tid + i * 256;
        int node = idx >> 4, c4 = idx & 15;
        int sp = species[nb + node];
        float4 v = reinterpret_cast<const float4*>(Wsp + (size_t)sp * 64)[c4];
        reinterpret_cast<float4*>(xs)[idx] = v;
        reinterpret_cast<float4*>(xi)[(size_t)(nb + node) * 16 + c4] = v;
    }
    {
        const float4* wsrc = reinterpret_cast<const float4*>(Wl0);
        float4* wd = reinterpret_cast<float4*>(ws);
        #pragma unroll
        for (int i = 0; i < 2; ++i) wd[tid + i * 256] = wsrc[tid + i * 256];
    }
    __syncthreads();

    int c4g = tid & 7;
    int nrow = tid >> 3;
    float4 acc = *reinterpret_cast<const float4*>(bl0 + c4g * 4);
    const float* xr = xs + nrow * 64;
    #pragma unroll 8
    for (int j = 0; j < 64; ++j) {
        float xv = xr[j];
        float4 wv = *reinterpret_cast<const float4*>(ws + j * 32 + c4g * 4);
        acc.x = fmaf(xv, wv.x, acc.x);
        acc.y = fmaf(xv, wv.y, acc.y);
        acc.z = fmaf(xv, wv.z, acc.z);
        acc.w = fmaf(xv, wv.w, acc.w);
    }
    *reinterpret_cast<float4*>(h + (size_t)(nb + nrow) * 32 + c4g * 4) = acc;
}

// ======================= merged setup kernel (1 dispatch) ===================
__global__ __launch_bounds__(256) void setup_kernel(
    const float* __restrict__ dist, const float* __restrict__ sw,
    const float* __restrict__ bo, u16* __restrict__ WTg,
    const int* __restrict__ species, const float* __restrict__ Wsp,
    const float* __restrict__ Wl0, const float* __restrict__ bl0,
    float* __restrict__ xi, float* __restrict__ h0,
    const float* __restrict__ fcW1, const float* __restrict__ fcW2,
    const float* __restrict__ fcW3, u16* __restrict__ Wpk,
    const int* __restrict__ esrc, int* __restrict__ rowp)
{
    __shared__ __align__(16) char smem[21760];
    int wk = blockIdx.x;
    if (wk < NW_EDGE)
        edge_wt_work(wk, dist, sw, bo, WTg, smem);
    else if (wk < NW_EDGE + NW_XI)
        xi_init_h_work(wk - NW_EDGE, species, Wsp, Wl0, bl0, xi, h0, smem);
    else if (wk < NW_EDGE + NW_XI + NW_PACK)
        pack_w_work(wk - NW_EDGE - NW_XI, fcW1, fcW2, fcW3, Wpk);
    else
        row_start_work(wk - NW_EDGE - NW_XI - NW_PACK, esrc, rowp);
}

// ======================= fused per-layer kernel =============================
__global__ __launch_bounds__(256) void agg_fc_fused(
    const u16* __restrict__ WTg,            // [NGROUPS][48][8] bf16
    const int* __restrict__ row,
    const int* __restrict__ dst,
    const float* __restrict__ h_in,         // N x 32
    float* __restrict__ h_out,              // N x 32 (next layer)
    const u16* __restrict__ Wpk,
    const float* __restrict__ b1,
    const float* __restrict__ b2,
    const float* __restrict__ b3,
    const float* __restrict__ Wl_next,      // 64 x 32 (if do_h)
    const float* __restrict__ bl_next,      // 32
    int do_h,
    float* __restrict__ xi)
{
    __shared__ __align__(16) char smem[21760 + 16 * CAP * 2];   // 31744 B
    u16 (*Xs)[XROW] = reinterpret_cast<u16(*)[XROW]>(smem);
    u16* mi  = reinterpret_cast<u16*>(smem + 21760);            // [16][CAP]
    u16* Y1  = reinterpret_cast<u16*>(smem + 21760);            // aliases mi
    u16* Y2  = reinterpret_cast<u16*>(smem + 21760 + 2304);
    float* Yo = reinterpret_cast<float*>(smem + 21760 + 4608);  // 16 x 68 f32
    float* Wlds = reinterpret_cast<float*>(smem);               // aliases Xs
    float* Xn   = reinterpret_cast<float*>(smem + 8192);        // 16 x 68 f32

    int tid = threadIdx.x;
    int wv = tid >> 6;
    int lane = tid & 63;
    int s = lane & 15;
    int kg = lane >> 4;
    int n0 = blockIdx.x * 16;
    int base = n0 + (wv << 2);

    int E0 = row[n0];
    int E1 = row[n0 + 16];
    int G0 = E0 & ~7;
    int nfill = E1 - G0;
    if (nfill > NFILL_MAX) nfill = NFILL_MAX;

    // ---- si staging + zero pad ----
    {
        int t = kg;
        u16* xr = &Xs[(wv << 2) + t][0];
        xr[640 + s] = f2bf(h_in[(size_t)(base + t) * 32 + s]);
        xr[656 + s] = 0;
    }

    // ---- block-local mi gather: thread-per-edge ----
    for (int i = tid; i < nfill; i += 256) {
        int d = dst[G0 + i];
        const float4* hp = reinterpret_cast<const float4*>(h_in + (size_t)d * 32 + 16);
        float4 v0 = hp[0], v1 = hp[1], v2 = hp[2], v3 = hp[3];
        u16* col = mi + i;
        col[0 * CAP]  = f2bf(v0.x); col[1 * CAP]  = f2bf(v0.y);
        col[2 * CAP]  = f2bf(v0.z); col[3 * CAP]  = f2bf(v0.w);
        col[4 * CAP]  = f2bf(v1.x); col[5 * CAP]  = f2bf(v1.y);
        col[6 * CAP]  = f2bf(v1.z); col[7 * CAP]  = f2bf(v1.w);
        col[8 * CAP]  = f2bf(v2.x); col[9 * CAP]  = f2bf(v2.y);
        col[10 * CAP] = f2bf(v2.z); col[11 * CAP] = f2bf(v2.w);
        col[12 * CAP] = f2bf(v3.x); col[13 * CAP] = f2bf(v3.y);
        col[14 * CAP] = f2bf(v3.z); col[15 * CAP] = f2bf(v3.w);
    }
    __syncthreads();

    // ======== Phase A: streaming MFMA aggregation ========
    for (int t = 0; t < 4; ++t) {
        int node = base + t;
        int e0 = row[node], e1 = row[node + 1];
        int e0a = e0 & ~7;
        int L0 = e0a - G0;                       // local aligned start (8-aligned)
        int nks = (e1 - e0a + 31) >> 5;

        f32x4 c0 = {0.f, 0.f, 0.f, 0.f};
        f32x4 c1 = {0.f, 0.f, 0.f, 0.f};
        f32x4 c2 = {0.f, 0.f, 0.f, 0.f};

        for (int kc = 0; kc < nks; ++kc) {
            int ebg = e0a + kc * 32 + kg * 8;    // global edge index (8-aligned)
            int ebl = L0 + kc * 32 + kg * 8;     // local (mi LDS)
            uint4 bu = *reinterpret_cast<const uint4*>(mi + s * CAP + ebl);
            {
                int lo = e0 - ebg, hi = e1 - ebg;
                ull vA = mge(lo) & ~mge(hi);
                ull vB = mge(lo - 4) & ~mge(hi - 4);
                ull* bp = reinterpret_cast<ull*>(&bu);
                bp[0] &= vA;
                bp[1] &= vB;
            }
            short8v bfrag = *reinterpret_cast<short8v*>(&bu);
            // A fragments: grouped layout -> 768B contiguous per group
            const u16* gp = WTg + (size_t)(ebg >> 3) * GSTRIDE + (size_t)s * 8;
            short8v a0 = *reinterpret_cast<const short8v*>(gp);
            short8v a1 = *reinterpret_cast<const short8v*>(gp + 128);
            short8v a2 = *reinterpret_cast<const short8v*>(gp + 256);
            c0 = __builtin_amdgcn_mfma_f32_16x16x32_bf16(a0, bfrag, c0, 0, 0, 0);
            c1 = __builtin_amdgcn_mfma_f32_16x16x32_bf16(a1, bfrag, c1, 0, 0, 0);
            c2 = __builtin_amdgcn_mfma_f32_16x16x32_bf16(a2, bfrag, c2, 0, 0, 0);
        }

        u16* xr = &Xs[(wv << 2) + t][0];
        #pragma unroll
        for (int q = 0; q < 4; ++q) {
            xr[(kg * 4 + q) * 16 + s]      = f2bf(c0[q]);
            xr[(16 + kg * 4 + q) * 16 + s] = f2bf(c1[q]);
        }
        if (kg < 2) {
            #pragma unroll
            for (int q = 0; q < 4; ++q)
                xr[(32 + kg * 4 + q) * 16 + s] = f2bf(c2[q]);
        }
    }
    __syncthreads();

    // ======== FC chain ========
    int w = wv;
    int lrow = lane & 15;
    int lk = lane >> 4;
    int col = w * 16 + lrow;

    const u16* Wpk1 = Wpk;
    const u16* Wpk2 = Wpk + W1PK;
    const u16* Wpk3 = Wpk + W1PK + W23PK;

    // ---- FC1: K = 672 ----
    f32x4 acc;
    {
        float bv = b1[col];
        acc[0] = bv; acc[1] = bv; acc[2] = bv; acc[3] = bv;
    }
    const u16* wp = Wpk1 + ((size_t)w * 64 + lane) * 8;
    #pragma unroll
    for (int ks = 0; ks < 21; ++ks) {
        short8v a = *reinterpret_cast<const short8v*>(&Xs[lrow][ks * 32 + lk * 8]);
        short8v b = *reinterpret_cast<const short8v*>(wp + (size_t)ks * 2048);
        acc = __builtin_amdgcn_mfma_f32_16x16x32_bf16(a, b, acc, 0, 0, 0);
    }
    __syncthreads();   // mi region fully dead before Y1 writes (mi aliased)
    #pragma unroll
    for (int q = 0; q < 4; ++q)
        Y1[(lk * 4 + q) * 72 + col] = f2bf(sspf(acc[q]));
    __syncthreads();

    // stage Wl_next into dead Xs region (concurrent with FC2/FC3)
    if (do_h) {
        const float4* wsrc = reinterpret_cast<const float4*>(Wl_next);
        float4* wd = reinterpret_cast<float4*>(Wlds);
        wd[tid] = wsrc[tid];
        wd[tid + 256] = wsrc[tid + 256];
    }

    // ---- FC2: K = 64 ----
    {
        float bv = b2[col];
        acc[0] = bv; acc[1] = bv; acc[2] = bv; acc[3] = bv;
    }
    #pragma unroll
    for (int ks = 0; ks < 2; ++ks) {
        short8v a = *reinterpret_cast<const short8v*>(&Y1[lrow * 72 + ks * 32 + lk * 8]);
        short8v b = *reinterpret_cast<const short8v*>(Wpk2 + ((size_t)(ks * 4 + w) * 64 + lane) * 8);
        acc = __builtin_amdgcn_mfma_f32_16x16x32_bf16(a, b, acc, 0, 0, 0);
    }
    __syncthreads();
    #pragma unroll
    for (int q = 0; q < 4; ++q)
        Y2[(lk * 4 + q) * 72 + col] = f2bf(sspf(acc[q]));
    __syncthreads();

    // ---- FC3: K = 64 ----
    {
        float bv = b3[col];
        acc[0] = bv; acc[1] = bv; acc[2] = bv; acc[3] = bv;
    }
    #pragma unroll
    for (int ks = 0; ks < 2; ++ks) {
        short8v a = *reinterpret_cast<const short8v*>(&Y2[lrow * 72 + ks * 32 + lk * 8]);
        short8v b = *reinterpret_cast<const short8v*>(Wpk3 + ((size_t)(ks * 4 + w) * 64 + lane) * 8);
        acc = __builtin_amdgcn_mfma_f32_16x16x32_bf16(a, b, acc, 0, 0, 0);
    }
    #pragma unroll
    for (int q = 0; q < 4; ++q)
        Yo[(lk * 4 + q) * 68 + col] = acc[q];
    __syncthreads();

    // ---- residual update (+ stash xi_new for h epilogue) ----
    {
        int rr = tid >> 4;
        int cc = tid & 15;
        float4 dv = *reinterpret_cast<const float4*>(Yo + rr * 68 + cc * 4);
        float4* xpn = reinterpret_cast<float4*>(xi + (size_t)(n0 + rr) * 64 + cc * 4);
        float4 o = *xpn;
        o.x += dv.x; o.y += dv.y; o.z += dv.z; o.w += dv.w;
        *xpn = o;
        if (do_h)
            *reinterpret_cast<float4*>(Xn + rr * 68 + cc * 4) = o;
    }

    // ---- h_next for own 16 nodes ----
    if (do_h) {
        __syncthreads();
        int node = tid >> 4;
        int c2 = (tid & 15) * 2;
        const float* xnr = Xn + node * 68;
        float h0 = bl_next[c2], h1 = bl_next[c2 + 1];
        #pragma unroll 8
        for (int j = 0; j < 64; ++j) {
            float xv = xnr[j];
            h0 = fmaf(xv, Wlds[j * 32 + c2], h0);
            h1 = fmaf(xv, Wlds[j * 32 + c2 + 1], h1);
        }
        *reinterpret_cast<float2*>(h_out + (size_t)(n0 + node) * 32 + c2) =
            make_float2(h0, h1);
    }
}

// ---------------------------------------------------------------------------
extern "C" void kernel_launch(void* const* d_in, const int* in_sizes, int n_in,
                              void* d_out, int out_size, void* d_ws, size_t ws_size,
                              hipStream_t stream) {
    const int*   species = (const int*)d_in[0];
    const int*   esrc    = (const int*)d_in[1];
    const int*   edst    = (const int*)d_in[2];
    const float* dist    = (const float*)d_in[3];
    const float* sw      = (const float*)d_in[4];
    const float* bo      = (const float*)d_in[5];
    const float* Wsp     = (const float*)d_in[6];
    const float* Wl      = (const float*)d_in[7];
    const float* bl      = (const float*)d_in[8];
    const float* fcW1    = (const float*)d_in[9];
    const float* fcb1    = (const float*)d_in[10];
    const float* fcW2    = (const float*)d_in[11];
    const float* fcb2    = (const float*)d_in[12];
    const float* fcW3    = (const float*)d_in[13];
    const float* fcb3    = (const float*)d_in[14];
    float* xi = (float*)d_out;

    char* ws = (char*)d_ws;
    u16*   WTg  = (u16*)ws;                     // NGROUPS*384*2 = 15,384,576 B
    int*   rowp = (int*)(ws + 15384576);        //     80,128 B
    float* h0   = (float*)(ws + 15464704);      //  2,560,000 B
    float* h1   = (float*)(ws + 18024704);      //  2,560,000 B
    u16*   Wpk  = (u16*)(ws + 20584704);        //    307,200 B

    hipLaunchKernelGGL(setup_kernel, dim3(NW_TOTAL), dim3(256), 0, stream,
                       dist, sw, bo, WTg,
                       species, Wsp, Wl, bl, xi, h0,
                       fcW1, fcW2, fcW3, Wpk,
                       esrc, rowp);

    float* hbuf[2] = {h0, h1};
    for (int l = 0; l < 3; ++l) {
        int do_h = (l < 2) ? 1 : 0;
        int lnext = do_h ? (l + 1) : l;
        hipLaunchKernelGGL(agg_fc_fused, dim3(NTILES), dim3(256), 0, stream,
                           WTg, rowp, edst,
                           hbuf[l & 1], hbuf[(l + 1) & 1],
                           Wpk + (size_t)l * WPK_LAYER,
                           fcb1 + (size_t)l * 64, fcb2 + (size_t)l * 64,
                           fcb3 + (size_t)l * 64,
                           Wl + (size_t)lnext * 64 * 32,
                           bl + (size_t)lnext * 32,
                           do_h, xi);
    }
}

// Round 18
// 84.109 us; speedup vs baseline: 1.1434x; 1.0382x over previous
//
#include <hip/hip_runtime.h>
#include <math.h>

#define N_NODES 20000
#define N_EDGES 160000
#define EPAD    160256
#define NGROUPS (EPAD / 8)     // 20032 8-edge groups
#define GSTRIDE 320            // u16 per group: 40 rows x 8 (no zero rows)
#define NTILES  1250

#define PI_F 3.14159265358979323846f
#define LN2_F 0.69314718055994530942f

#define W1PK 43008
#define W23PK 4096
#define WPK_LAYER 51200
#define WLPK_LAYER 2048    // per-next-layer packed Wl: 2 ksteps x 2 cfrags x 64 x 8
#define XROW 680           // LDS X row stride in u16
#define CAP 312            // mi LDS row stride in u16
#define NFILL_MAX 272

#define NW_EDGE 626        // edge_wt tiles (256 edges = 32 groups each)
#define NW_XI   625
#define NW_PACK 616        // (3*51200 + 2*2048) / 256 = 616
#define NW_ROW  79
#define NW_TOTAL (NW_EDGE + NW_XI + NW_PACK + NW_ROW)

typedef short short8v __attribute__((ext_vector_type(8)));
typedef float f32x4 __attribute__((ext_vector_type(4)));
typedef unsigned short u16;
typedef unsigned long long ull;

__device__ __forceinline__ float sspf(float x) {
    return fmaxf(x, 0.0f) + log1pf(expf(-fabsf(x))) - LN2_F;
}
__device__ __forceinline__ u16 f2bf(float f) {
    unsigned int u = __float_as_uint(f);
    return (u16)((u + 0x7fffu + ((u >> 16) & 1u)) >> 16);
}
__device__ __forceinline__ unsigned int pk2(float a, float b) {
    return (unsigned int)f2bf(a) | ((unsigned int)f2bf(b) << 16);
}
// mask of 4 u16 slots: slots j >= t are 0xFFFF (t clamped to [0,4])
__device__ __forceinline__ ull mge(int t) {
    t = t < 0 ? 0 : (t > 4 ? 4 : t);
    return t == 4 ? 0ULL : (~0ULL << (t * 16));
}

// ======================= setup works (shared smem) ==========================
__device__ void edge_wt_work(int blk, const float* __restrict__ dist,
                             const float* __restrict__ sw,
                             const float* __restrict__ bo,
                             u16* __restrict__ WTg, char* smem)
{
    u16 (*tr)[264] = reinterpret_cast<u16(*)[264]>(smem);   // 21120 B
    int tid = threadIdx.x;
    int e = blk * 256 + tid;

    if (e < N_EDGES) {
        float r = dist[e];
        float c = sqrtf(0.4f) / r * sw[e];
        float th = PI_F * r * 0.2f;
        float s1, c1;
        __sincosf(th, &s1, &c1);
        float k2c = 2.0f * c1;
        float rbv[8];
        rbv[0] = s1;
        float sp = 0.0f, sc = s1;
        #pragma unroll
        for (int n = 1; n < 8; ++n) {
            float sn = k2c * sc - sp;
            rbv[n] = sn;
            sp = sc; sc = sn;
        }
        #pragma unroll
        for (int n = 0; n < 8; ++n) rbv[n] *= c;
        float bov[5];
        #pragma unroll
        for (int b = 0; b < 5; ++b) bov[b] = bo[(size_t)e * 5 + b];
        #pragma unroll
        for (int n = 0; n < 8; ++n)
            #pragma unroll
            for (int b = 0; b < 5; ++b)
                tr[n * 5 + b][tid] = f2bf(rbv[n] * bov[b]);
    } else {
        #pragma unroll
        for (int j = 0; j < 40; ++j) tr[j][tid] = 0;
    }
    __syncthreads();

    // write 32 groups x 40 rows x 8 u16, coalesced
    #pragma unroll
    for (int i = 0; i < 5; ++i) {
        int r = i * 8 + (tid & 7);
        int gl = tid >> 3;                       // 0..31
        uint4 v = *reinterpret_cast<const uint4*>(&tr[r][gl * 8]);
        *reinterpret_cast<uint4*>(
            WTg + ((size_t)(blk * 32 + gl) * GSTRIDE + r * 8)) = v;
    }
}

__device__ void row_start_work(int blk, const int* __restrict__ src,
                               int* __restrict__ row)
{
    int i = blk * 256 + threadIdx.x;
    if (i > N_NODES) return;
    int lo = 0, hi = N_EDGES;
    while (lo < hi) {
        int mid = (lo + hi) >> 1;
        if (src[mid] < i) lo = mid + 1; else hi = mid;
    }
    row[i] = lo;
}

__device__ void pack_w_work(int blk, const float* __restrict__ fcW1,
                            const float* __restrict__ fcW2,
                            const float* __restrict__ fcW3,
                            const float* __restrict__ Wl,
                            u16* __restrict__ Wpk,
                            u16* __restrict__ Wlpk)
{
    int idx = blk * 256 + threadIdx.x;
    if (idx >= 3 * WPK_LAYER + 2 * WLPK_LAYER) return;
    if (idx >= 3 * WPK_LAYER) {
        // pack Wl layers 1,2 (used as "next" by layers 0,1): B-frag bf16
        int r2 = idx - 3 * WPK_LAYER;
        int layer2 = r2 >> 11;                 // 0..1
        int e = r2 & 2047;
        int j = e & 7, lane = (e >> 3) & 63;
        int rest = e >> 9;                     // ks*2 + cf
        int ks = rest >> 1, cf = rest & 1;
        int k = ks * 32 + (lane >> 4) * 8 + j;
        int col = cf * 16 + (lane & 15);
        Wlpk[(size_t)layer2 * WLPK_LAYER + e] =
            f2bf(Wl[(size_t)(layer2 + 1) * 64 * 32 + (size_t)k * 32 + col]);
        return;
    }
    int layer = idx / WPK_LAYER;
    int r = idx - layer * WPK_LAYER;
    float val = 0.0f;
    if (r < W1PK) {
        int e = r;
        int j = e & 7, lane = (e >> 3) & 63, c16 = (e >> 9) & 3, ks = e >> 11;
        int k = ks * 32 + (lane >> 4) * 8 + j;
        int colm = c16 * 16 + (lane & 15);
        if (k < 640) {
            int nbv = k >> 4, ss = k & 15;
            int nn = nbv / 5, bb = nbv - nn * 5;
            val = fcW1[(size_t)layer * 656 * 64 + (size_t)(nn * 80 + ss * 5 + bb) * 64 + colm];
        } else if (k < 656) {
            val = fcW1[(size_t)layer * 656 * 64 + (size_t)k * 64 + colm];
        }
    } else {
        bool is2 = (r < W1PK + W23PK);
        const float* W = is2 ? fcW2 : fcW3;
        int e = is2 ? (r - W1PK) : (r - W1PK - W23PK);
        int j = e & 7, lane = (e >> 3) & 63, c16 = (e >> 9) & 3, ks = e >> 11;
        int k = ks * 32 + (lane >> 4) * 8 + j;
        int colm = c16 * 16 + (lane & 15);
        val = W[(size_t)layer * 64 * 64 + (size_t)k * 64 + colm];
    }
    Wpk[(size_t)layer * WPK_LAYER + r] = f2bf(val);
}

__device__ void xi_init_h_work(int blk, const int* __restrict__ species,
                               const float* __restrict__ Wsp,
                               const float* __restrict__ Wl0,
                               const float* __restrict__ bl0,
                               float* __restrict__ xi,
                               float* __restrict__ h, char* smem)
{
    float* xs = reinterpret_cast<float*>(smem);            //  8192 B
    float* ws = reinterpret_cast<float*>(smem + 8192);     //  8192 B
    int tid = threadIdx.x;
    int nb = blk * 32;

    #pragma unroll
    for (int i = 0; i < 2; ++i) {
        int idx = tid + i * 256;
        int node = idx >> 4, c4 = idx & 15;
        int sp = species[nb + node];
        float4 v = reinterpret_cast<const float4*>(Wsp + (size_t)sp * 64)[c4];
        reinterpret_cast<float4*>(xs)[idx] = v;
        reinterpret_cast<float4*>(xi)[(size_t)(nb + node) * 16 + c4] = v;
    }
    {
        const float4* wsrc = reinterpret_cast<const float4*>(Wl0);
        float4* wd = reinterpret_cast<float4*>(ws);
        #pragma unroll
        for (int i = 0; i < 2; ++i) wd[tid + i * 256] = wsrc[tid + i * 256];
    }
    __syncthreads();

    int c4g = tid & 7;
    int nrow = tid >> 3;
    float4 acc = *reinterpret_cast<const float4*>(bl0 + c4g * 4);
    const float* xr = xs + nrow * 64;
    #pragma unroll 8
    for (int j = 0; j < 64; ++j) {
        float xv = xr[j];
        float4 wv = *reinterpret_cast<const float4*>(ws + j * 32 + c4g * 4);
        acc.x = fmaf(xv, wv.x, acc.x);
        acc.y = fmaf(xv, wv.y, acc.y);
        acc.z = fmaf(xv, wv.z, acc.z);
        acc.w = fmaf(xv, wv.w, acc.w);
    }
    *reinterpret_cast<float4*>(h + (size_t)(nb + nrow) * 32 + c4g * 4) = acc;
}

// ======================= merged setup kernel (1 dispatch) ===================
__global__ __launch_bounds__(256) void setup_kernel(
    const float* __restrict__ dist, const float* __restrict__ sw,
    const float* __restrict__ bo, u16* __restrict__ WTg,
    const int* __restrict__ species, const float* __restrict__ Wsp,
    const float* __restrict__ Wl, const float* __restrict__ bl0,
    float* __restrict__ xi, float* __restrict__ h0,
    const float* __restrict__ fcW1, const float* __restrict__ fcW2,
    const float* __restrict__ fcW3, u16* __restrict__ Wpk,
    u16* __restrict__ Wlpk,
    const int* __restrict__ esrc, int* __restrict__ rowp)
{
    __shared__ __align__(16) char smem[21760];
    int wk = blockIdx.x;
    if (wk < NW_EDGE)
        edge_wt_work(wk, dist, sw, bo, WTg, smem);
    else if (wk < NW_EDGE + NW_XI)
        xi_init_h_work(wk - NW_EDGE, species, Wsp, Wl, bl0, xi, h0, smem);
    else if (wk < NW_EDGE + NW_XI + NW_PACK)
        pack_w_work(wk - NW_EDGE - NW_XI, fcW1, fcW2, fcW3, Wl, Wpk, Wlpk);
    else
        row_start_work(wk - NW_EDGE - NW_XI - NW_PACK, esrc, rowp);
}

// ======================= fused per-layer kernel =============================
__global__ __launch_bounds__(256) void agg_fc_fused(
    const u16* __restrict__ WTg,            // [NGROUPS][40][8] bf16
    const int* __restrict__ row,
    const int* __restrict__ dst,
    const float* __restrict__ h_in,         // N x 32
    float* __restrict__ h_out,              // N x 32 (next layer)
    const u16* __restrict__ Wpk,
    const float* __restrict__ b1,
    const float* __restrict__ b2,
    const float* __restrict__ b3,
    const u16* __restrict__ Wlpk_l,         // packed Wl_next (if do_h)
    const float* __restrict__ bl_next,      // 32
    int do_h,
    float* __restrict__ xi)
{
    __shared__ __align__(16) char smem[21760 + 16 * CAP * 2];   // 31744 B
    u16 (*Xs)[XROW] = reinterpret_cast<u16(*)[XROW]>(smem);
    u16* mi  = reinterpret_cast<u16*>(smem + 21760);            // [16][CAP]
    u16* Y1  = reinterpret_cast<u16*>(smem + 21760);            // aliases mi
    u16* Y2  = reinterpret_cast<u16*>(smem + 21760 + 2304);
    float* Yo = reinterpret_cast<float*>(smem + 21760 + 4608);  // 16 x 68 f32
    u16* Xnb  = reinterpret_cast<u16*>(smem + 8192);            // 16 x 64 bf16 (dead Xs)

    int tid = threadIdx.x;
    int wv = tid >> 6;
    int lane = tid & 63;
    int s = lane & 15;
    int kg = lane >> 4;
    int n0 = blockIdx.x * 16;
    int base = n0 + (wv << 2);

    int E0 = row[n0];
    int E1 = row[n0 + 16];
    int G0 = E0 & ~7;
    int nfill = E1 - G0;
    if (nfill > NFILL_MAX) nfill = NFILL_MAX;

    // ---- si staging + zero pad ----
    {
        int t = kg;
        u16* xr = &Xs[(wv << 2) + t][0];
        xr[640 + s] = f2bf(h_in[(size_t)(base + t) * 32 + s]);
        xr[656 + s] = 0;
    }

    // ---- block-local mi gather: thread-per-edge ----
    for (int i = tid; i < nfill; i += 256) {
        int d = dst[G0 + i];
        const float4* hp = reinterpret_cast<const float4*>(h_in + (size_t)d * 32 + 16);
        float4 v0 = hp[0], v1 = hp[1], v2 = hp[2], v3 = hp[3];
        u16* col = mi + i;
        col[0 * CAP]  = f2bf(v0.x); col[1 * CAP]  = f2bf(v0.y);
        col[2 * CAP]  = f2bf(v0.z); col[3 * CAP]  = f2bf(v0.w);
        col[4 * CAP]  = f2bf(v1.x); col[5 * CAP]  = f2bf(v1.y);
        col[6 * CAP]  = f2bf(v1.z); col[7 * CAP]  = f2bf(v1.w);
        col[8 * CAP]  = f2bf(v2.x); col[9 * CAP]  = f2bf(v2.y);
        col[10 * CAP] = f2bf(v2.z); col[11 * CAP] = f2bf(v2.w);
        col[12 * CAP] = f2bf(v3.x); col[13 * CAP] = f2bf(v3.y);
        col[14 * CAP] = f2bf(v3.z); col[15 * CAP] = f2bf(v3.w);
    }
    __syncthreads();

    // ======== Phase A: streaming MFMA aggregation ========
    for (int t = 0; t < 4; ++t) {
        int node = base + t;
        int e0 = row[node], e1 = row[node + 1];
        int e0a = e0 & ~7;
        int L0 = e0a - G0;
        int nks = (e1 - e0a + 31) >> 5;

        f32x4 c0 = {0.f, 0.f, 0.f, 0.f};
        f32x4 c1 = {0.f, 0.f, 0.f, 0.f};
        f32x4 c2 = {0.f, 0.f, 0.f, 0.f};

        for (int kc = 0; kc < nks; ++kc) {
            int ebg = e0a + kc * 32 + kg * 8;
            int ebl = L0 + kc * 32 + kg * 8;
            uint4 bu = *reinterpret_cast<const uint4*>(mi + s * CAP + ebl);
            {
                int lo = e0 - ebg, hi = e1 - ebg;
                ull vA = mge(lo) & ~mge(hi);
                ull vB = mge(lo - 4) & ~mge(hi - 4);
                ull* bp = reinterpret_cast<ull*>(&bu);
                bp[0] &= vA;
                bp[1] &= vB;
            }
            short8v bfrag = *reinterpret_cast<short8v*>(&bu);
            const u16* gp = WTg + (size_t)(ebg >> 3) * GSTRIDE + (size_t)s * 8;
            short8v a0 = *reinterpret_cast<const short8v*>(gp);
            short8v a1 = *reinterpret_cast<const short8v*>(gp + 128);
            short8v a2 = {0, 0, 0, 0, 0, 0, 0, 0};
            if (s < 8)
                a2 = *reinterpret_cast<const short8v*>(gp + 256);
            c0 = __builtin_amdgcn_mfma_f32_16x16x32_bf16(a0, bfrag, c0, 0, 0, 0);
            c1 = __builtin_amdgcn_mfma_f32_16x16x32_bf16(a1, bfrag, c1, 0, 0, 0);
            c2 = __builtin_amdgcn_mfma_f32_16x16x32_bf16(a2, bfrag, c2, 0, 0, 0);
        }

        u16* xr = &Xs[(wv << 2) + t][0];
        #pragma unroll
        for (int q = 0; q < 4; ++q) {
            xr[(kg * 4 + q) * 16 + s]      = f2bf(c0[q]);
            xr[(16 + kg * 4 + q) * 16 + s] = f2bf(c1[q]);
        }
        if (kg < 2) {
            #pragma unroll
            for (int q = 0; q < 4; ++q)
                xr[(32 + kg * 4 + q) * 16 + s] = f2bf(c2[q]);
        }
    }
    __syncthreads();

    // ======== FC chain ========
    int w = wv;
    int lrow = lane & 15;
    int lk = lane >> 4;
    int col = w * 16 + lrow;

    const u16* Wpk1 = Wpk;
    const u16* Wpk2 = Wpk + W1PK;
    const u16* Wpk3 = Wpk + W1PK + W23PK;

    // ---- FC1: K = 672 ----
    f32x4 acc;
    {
        float bv = b1[col];
        acc[0] = bv; acc[1] = bv; acc[2] = bv; acc[3] = bv;
    }
    const u16* wp = Wpk1 + ((size_t)w * 64 + lane) * 8;
    #pragma unroll
    for (int ks = 0; ks < 21; ++ks) {
        short8v a = *reinterpret_cast<const short8v*>(&Xs[lrow][ks * 32 + lk * 8]);
        short8v b = *reinterpret_cast<const short8v*>(wp + (size_t)ks * 2048);
        acc = __builtin_amdgcn_mfma_f32_16x16x32_bf16(a, b, acc, 0, 0, 0);
    }
    __syncthreads();   // mi region fully dead before Y1 writes (mi aliased)
    #pragma unroll
    for (int q = 0; q < 4; ++q)
        Y1[(lk * 4 + q) * 72 + col] = f2bf(sspf(acc[q]));
    __syncthreads();

    // ---- FC2: K = 64 ----
    {
        float bv = b2[col];
        acc[0] = bv; acc[1] = bv; acc[2] = bv; acc[3] = bv;
    }
    #pragma unroll
    for (int ks = 0; ks < 2; ++ks) {
        short8v a = *reinterpret_cast<const short8v*>(&Y1[lrow * 72 + ks * 32 + lk * 8]);
        short8v b = *reinterpret_cast<const short8v*>(Wpk2 + ((size_t)(ks * 4 + w) * 64 + lane) * 8);
        acc = __builtin_amdgcn_mfma_f32_16x16x32_bf16(a, b, acc, 0, 0, 0);
    }
    __syncthreads();
    #pragma unroll
    for (int q = 0; q < 4; ++q)
        Y2[(lk * 4 + q) * 72 + col] = f2bf(sspf(acc[q]));
    __syncthreads();

    // ---- FC3: K = 64 ----
    {
        float bv = b3[col];
        acc[0] = bv; acc[1] = bv; acc[2] = bv; acc[3] = bv;
    }
    #pragma unroll
    for (int ks = 0; ks < 2; ++ks) {
        short8v a = *reinterpret_cast<const short8v*>(&Y2[lrow * 72 + ks * 32 + lk * 8]);
        short8v b = *reinterpret_cast<const short8v*>(Wpk3 + ((size_t)(ks * 4 + w) * 64 + lane) * 8);
        acc = __builtin_amdgcn_mfma_f32_16x16x32_bf16(a, b, acc, 0, 0, 0);
    }
    #pragma unroll
    for (int q = 0; q < 4; ++q)
        Yo[(lk * 4 + q) * 68 + col] = acc[q];
    __syncthreads();

    // ---- residual update (+ stash xi_new bf16 for h epilogue) ----
    {
        int rr = tid >> 4;
        int cc = tid & 15;
        float4 dv = *reinterpret_cast<const float4*>(Yo + rr * 68 + cc * 4);
        float4* xpn = reinterpret_cast<float4*>(xi + (size_t)(n0 + rr) * 64 + cc * 4);
        float4 o = *xpn;
        o.x += dv.x; o.y += dv.y; o.z += dv.z; o.w += dv.w;
        *xpn = o;
        if (do_h) {
            unsigned int* xb = reinterpret_cast<unsigned int*>(Xnb + rr * 64 + cc * 4);
            xb[0] = pk2(o.x, o.y);
            xb[1] = pk2(o.z, o.w);
        }
    }

    // ---- h_next via MFMA: h = Xnb(16x64) @ Wl_next(64x32), waves 0-1 ----
    if (do_h) {
        __syncthreads();
        if (wv < 2) {
            int cf = wv;
            f32x4 hacc;
            {
                float bv = bl_next[cf * 16 + lrow];
                hacc[0] = bv; hacc[1] = bv; hacc[2] = bv; hacc[3] = bv;
            }
            #pragma unroll
            for (int ks = 0; ks < 2; ++ks) {
                short8v a = *reinterpret_cast<const short8v*>(
                    Xnb + lrow * 64 + ks * 32 + lk * 8);
                short8v b = *reinterpret_cast<const short8v*>(
                    Wlpk_l + ((size_t)(ks * 2 + cf) * 64 + lane) * 8);
                hacc = __builtin_amdgcn_mfma_f32_16x16x32_bf16(a, b, hacc, 0, 0, 0);
            }
            #pragma unroll
            for (int q = 0; q < 4; ++q)
                h_out[(size_t)(n0 + lk * 4 + q) * 32 + cf * 16 + lrow] = hacc[q];
        }
    }
}

// ---------------------------------------------------------------------------
extern "C" void kernel_launch(void* const* d_in, const int* in_sizes, int n_in,
                              void* d_out, int out_size, void* d_ws, size_t ws_size,
                              hipStream_t stream) {
    const int*   species = (const int*)d_in[0];
    const int*   esrc    = (const int*)d_in[1];
    const int*   edst    = (const int*)d_in[2];
    const float* dist    = (const float*)d_in[3];
    const float* sw      = (const float*)d_in[4];
    const float* bo      = (const float*)d_in[5];
    const float* Wsp     = (const float*)d_in[6];
    const float* Wl      = (const float*)d_in[7];
    const float* bl      = (const float*)d_in[8];
    const float* fcW1    = (const float*)d_in[9];
    const float* fcb1    = (const float*)d_in[10];
    const float* fcW2    = (const float*)d_in[11];
    const float* fcb2    = (const float*)d_in[12];
    const float* fcW3    = (const float*)d_in[13];
    const float* fcb3    = (const float*)d_in[14];
    float* xi = (float*)d_out;

    char* ws = (char*)d_ws;
    u16*   WTg  = (u16*)ws;                     // NGROUPS*320*2 = 12,820,480 B
    int*   rowp = (int*)(ws + 12820480);        //     80,128 B
    float* h0   = (float*)(ws + 12900608);      //  2,560,000 B
    float* h1   = (float*)(ws + 15460608);      //  2,560,000 B
    u16*   Wpk  = (u16*)(ws + 18020608);        //    307,200 B
    u16*   Wlpk = (u16*)(ws + 18327808);        //      8,192 B

    hipLaunchKernelGGL(setup_kernel, dim3(NW_TOTAL), dim3(256), 0, stream,
                       dist, sw, bo, WTg,
                       species, Wsp, Wl, bl, xi, h0,
                       fcW1, fcW2, fcW3, Wpk, Wlpk,
                       esrc, rowp);

    float* hbuf[2] = {h0, h1};
    for (int l = 0; l < 3; ++l) {
        int do_h = (l < 2) ? 1 : 0;
        hipLaunchKernelGGL(agg_fc_fused, dim3(NTILES), dim3(256), 0, stream,
                           WTg, rowp, edst,
                           hbuf[l & 1], hbuf[(l + 1) & 1],
                           Wpk + (size_t)l * WPK_LAYER,
                           fcb1 + (size_t)l * 64, fcb2 + (size_t)l * 64,
                           fcb3 + (size_t)l * 64,
                           Wlpk + (size_t)(do_h ? l : 0) * WLPK_LAYER,
                           bl + (size_t)(l + (do_h ? 1 : 0)) * 32,
                           do_h, xi);
    }
}